// Round 6
// baseline (825.215 us; speedup 1.0000x reference)
//
#include <hip/hip_runtime.h>
#include <hip/hip_bf16.h>
#include <cstdint>

// ---- problem constants (B=4,S=2048,D=1024,E=8,F=4096, top-2, cap 1.25) ----
#define T_TOK 8192
#define D_DIM 1024
#define E_NUM 8
#define F_DIM 4096
#define CAP   1280          // ceil(8192*1.25/8)
#define ROWS  (E_NUM*CAP)   // 10240 (row index ROWS == dump/dropped)

typedef float  f32x4  __attribute__((ext_vector_type(4)));
typedef __bf16 bf16x8 __attribute__((ext_vector_type(8)));

__device__ __forceinline__ unsigned short f2bf(float f) {
  union { float f; unsigned int u; } v; v.f = f;
  unsigned int r = v.u + 0x7FFFu + ((v.u >> 16) & 1u);   // RNE
  return (unsigned short)(r >> 16);
}

// async global->LDS, 16B per lane; LDS dest is wave-uniform base + lane*16
#define GLL16(g, l) __builtin_amdgcn_global_load_lds( \
    (__attribute__((address_space(1))) void*)(g),      \
    (__attribute__((address_space(3))) void*)(l), 16, 0, 0)

#define BAR() __builtin_amdgcn_s_barrier()
#define PRIO1 __builtin_amdgcn_s_setprio(1)
#define PRIO0 __builtin_amdgcn_s_setprio(0)
#define LGKM0 do { asm volatile("s_waitcnt lgkmcnt(0)" ::: "memory"); \
                   __builtin_amdgcn_sched_barrier(0); } while (0)
#define VMCNT_LIT(n) asm volatile("s_waitcnt vmcnt(" #n ")" ::: "memory")
// bank-conflict swizzle for [rows][128B] LDS tiles: XOR 16B-chunk idx (bits
// 4-6) with row&7 (bits 7-9). Involution; same map on write-source and read.
#define SWZ(X) ((X) ^ ((((X) >> 7) & 7) << 4))

// ---------------- fp32 -> bf16 weight conversion ----------------
__global__ void convert_kernel(const float4* __restrict__ src,
                               ushort4* __restrict__ dst, int n4) {
  int i = blockIdx.x * blockDim.x + threadIdx.x;
  int stride = gridDim.x * blockDim.x;
  for (; i < n4; i += stride) {
    float4 v = src[i];
    ushort4 o;
    o.x = f2bf(v.x); o.y = f2bf(v.y); o.z = f2bf(v.z); o.w = f2bf(v.w);
    dst[i] = o;
  }
}

// ---------------- router: fp32 logits, top-2, softmax, aux accum ----------------
__global__ __launch_bounds__(256) void router_kernel(
    const float* __restrict__ x, const float* __restrict__ gw,
    int2* __restrict__ idx, float2* __restrict__ rw,
    int* __restrict__ counts, float* __restrict__ probs_sum) {
  __shared__ float gws[E_NUM * D_DIM];      // 32 KB
  __shared__ float lprob[E_NUM];
  __shared__ int   lcnt[E_NUM];
  int tid = threadIdx.x;
  {
    const float4* s = (const float4*)gw;
    float4* d = (float4*)gws;
    for (int i = tid; i < (E_NUM * D_DIM) / 4; i += 256) d[i] = s[i];
  }
  if (tid < E_NUM) { lprob[tid] = 0.f; lcnt[tid] = 0; }
  __syncthreads();

  int wave = tid >> 6, lane = tid & 63;
  int t = blockIdx.x * 4 + wave;
  float acc[E_NUM] = {};
  for (int i = 0; i < D_DIM / 64; ++i) {
    int d = i * 64 + lane;
    float xv = x[(size_t)t * D_DIM + d];
#pragma unroll
    for (int e = 0; e < E_NUM; ++e) acc[e] += xv * gws[e * D_DIM + d];
  }
#pragma unroll
  for (int e = 0; e < E_NUM; ++e)
#pragma unroll
    for (int off = 32; off; off >>= 1) acc[e] += __shfl_xor(acc[e], off);

  if (lane == 0) {
    int i1 = 0; float v1 = acc[0];
#pragma unroll
    for (int e = 1; e < E_NUM; ++e) if (acc[e] > v1) { v1 = acc[e]; i1 = e; }
    int i2 = -1; float v2 = -3.4e38f;
#pragma unroll
    for (int e = 0; e < E_NUM; ++e)
      if (e != i1 && acc[e] > v2) { v2 = acc[e]; i2 = e; }
    float e2 = expf(v2 - v1);          // v1 >= v2
    float s  = 1.f + e2;
    int2 ii; ii.x = i1; ii.y = i2; idx[t] = ii;
    float2 ww; ww.x = 1.f / s; ww.y = e2 / s; rw[t] = ww;
    atomicAdd(&lcnt[i1], 1); atomicAdd(&lcnt[i2], 1);
    float se = 0.f, p[E_NUM];
#pragma unroll
    for (int e = 0; e < E_NUM; ++e) { p[e] = expf(acc[e] - v1); se += p[e]; }
    float inv = 1.f / se;
#pragma unroll
    for (int e = 0; e < E_NUM; ++e) atomicAdd(&lprob[e], p[e] * inv);
  }
  __syncthreads();
  if (tid < E_NUM) {
    atomicAdd(&probs_sum[tid], lprob[tid]);
    atomicAdd(&counts[tid], lcnt[tid]);
  }
}

// ---------------- capacity scan (order-exact cumsum over 16384 slots) + aux ----------------
__global__ __launch_bounds__(1024) void scan_kernel(
    const int2* __restrict__ idx, int* __restrict__ slot,
    const int* __restrict__ counts, const float* __restrict__ probs_sum,
    float* __restrict__ aux) {
  __shared__ int sc[1024][E_NUM];   // 32 KB
  int tid = threadIdx.x;
  int fe[16];
  int lc[E_NUM] = {};
#pragma unroll
  for (int j = 0; j < 16; ++j) {
    int s = tid * 16 + j;
    int2 p = idx[s >> 1];
    int e = (s & 1) ? p.y : p.x;
    fe[j] = e; lc[e]++;
  }
#pragma unroll
  for (int e = 0; e < E_NUM; ++e) sc[tid][e] = lc[e];
  __syncthreads();
  for (int off = 1; off < 1024; off <<= 1) {
    int v[E_NUM];
    bool has = (tid >= off);
    if (has) {
#pragma unroll
      for (int e = 0; e < E_NUM; ++e) v[e] = sc[tid - off][e];
    }
    __syncthreads();
    if (has) {
#pragma unroll
      for (int e = 0; e < E_NUM; ++e) sc[tid][e] += v[e];
    }
    __syncthreads();
  }
  int pre[E_NUM];
#pragma unroll
  for (int e = 0; e < E_NUM; ++e) pre[e] = tid ? sc[tid - 1][e] : 0;
  int run[E_NUM] = {};
#pragma unroll
  for (int j = 0; j < 16; ++j) {
    int e = fe[j];
    int rank = pre[e] + run[e];
    run[e]++;
    slot[tid * 16 + j] = (rank < CAP) ? (e * CAP + rank) : ROWS;
  }
  if (tid == 0) {
    float s = 0.f;
    for (int e = 0; e < E_NUM; ++e) s += (float)counts[e] * probs_sum[e];
    aux[0] = 0.01f * (float)E_NUM * s / ((float)T_TOK * (float)T_TOK);
  }
}

// ---------------- dispatch x -> eb (bf16), skip dropped slots ----------------
__global__ void dispatch_kernel(const float* __restrict__ x,
                                const int* __restrict__ slot,
                                unsigned short* __restrict__ eb) {
  int s = blockIdx.x, lane = threadIdx.x;   // 64 threads
  int row = slot[s];
  if (row >= ROWS) return;
  int t = s >> 1;
  const float4* xs = (const float4*)(x + (size_t)t * D_DIM);
  ushort4* ed = (ushort4*)(eb + (size_t)row * D_DIM);
#pragma unroll
  for (int j = 0; j < 4; ++j) {
    float4 v = xs[j * 64 + lane];
    ushort4 o;
    o.x = f2bf(v.x); o.y = f2bf(v.y); o.z = f2bf(v.z); o.w = f2bf(v.w);
    ed[j * 64 + lane] = o;
  }
}

// ---- shared 8-phase K-loop machinery (256-row x 256-"col" tile, BK=64) ----
// Buffers: buf0 = even K-tiles, buf1 = odd. Staging discipline: ALL 4
// half-tiles (8 loads/wave) of tile 2it+1 issue in ONE burst at ph1 (buf1's
// free-window start), waited at end of ph4 (vmcnt(0): only that tile is in
// flight there). Tile 2it+2 issues at ph5, waited end of ph8. Cover = 3.5
// phases ~= 1200+ cyc > 900 cyc HBM latency.
#define QUAD(QA, QB) \
  { _Pragma("unroll") for (int m2 = 0; m2 < 4; ++m2) { \
    _Pragma("unroll") for (int n2 = 0; n2 < 2; ++n2) { \
      acc[(QA)*4+m2][(QB)*2+n2] = __builtin_amdgcn_mfma_f32_16x16x32_bf16( \
        a[m2][0], bb[(QB)*2+n2][0], acc[(QA)*4+m2][(QB)*2+n2], 0, 0, 0); \
      acc[(QA)*4+m2][(QB)*2+n2] = __builtin_amdgcn_mfma_f32_16x16x32_bf16( \
        a[m2][1], bb[(QB)*2+n2][1], acc[(QA)*4+m2][(QB)*2+n2], 0, 0, 0); \
  } } }

// ---------------- GEMM1: 256x(128+128) 8-phase, BK=64, 8 waves ----------------
// A = eb rows [c0,c0+256); B rows 0-127 = w1[f0..f0+128), 128-255 = w3[...).
// Waves: wm=w>>2 (A-half), wn=w&3; wn<2 -> s1, wn>=2 -> s3 (same cols).
// Epilogue: w3 waves dump acc (f32) to LDS; w1 waves compute silu(s1)*s3.
__global__ __launch_bounds__(512) void gemm1_kernel(
    const unsigned short* __restrict__ eb,   // [ROWS][D]
    const unsigned short* __restrict__ w1b,  // [E][F][D]
    const unsigned short* __restrict__ w3b,
    unsigned short* __restrict__ h) {        // [ROWS][F]
  __shared__ __align__(16) char smem[131072];
  const int e = blockIdx.z, c0 = blockIdx.y * 256, f0 = blockIdx.x * 128;
  const int tid = threadIdx.x, w = tid >> 6, lane = tid & 63;
  const int wm = w >> 2, wn = w & 3;
  const int fr = lane & 15, q16 = (lane >> 4) * 16;
  const int brow0 = (wn & 1) * 64;
  const int Abase0 = (0 + wm) * 16384;
  const int Abase1 = (2 + wm) * 16384;
  const int Bbase0 = 65536 + (0 + (wn >> 1)) * 16384;
  const int Bbase1 = 65536 + (2 + (wn >> 1)) * 16384;

  const int L0 = w * 1024 + lane * 16;
  const int L1 = 8192 + L0;
  const int P0 = SWZ(L0);
  const int P1 = SWZ(L1);
  const size_t go0 = (size_t)(P0 >> 7) * 2048 + (P0 & 127);
  const size_t go1 = (size_t)(P1 >> 7) * 2048 + (P1 & 127);
  const char* gb0 = (const char*)(w1b + ((size_t)e * F_DIM + f0) * D_DIM);
  const char* gb1 = (const char*)(w3b + ((size_t)e * F_DIM + f0) * D_DIM);
  const char* gb2 = (const char*)(eb + (size_t)(e * CAP + c0) * D_DIM);
  const char* gb3 = (const char*)(eb + (size_t)(e * CAP + c0 + 128) * D_DIM);

  // stage ALL 4 half-tiles of tile t into buffer (t&1)
  auto STAGE4 = [&](int t) {
    int b = (t & 1) * 2;
#pragma unroll
    for (int ht = 0; ht < 4; ++ht) {
      int lb = ((ht >= 2) ? 0 : 65536) + (b + (ht & 1)) * 16384;
      const char* g = (ht == 0 ? gb0 : ht == 1 ? gb1 : ht == 2 ? gb2 : gb3)
                      + (size_t)t * 128;
      char* lu = smem + lb + w * 1024;
      GLL16(g + go0, lu);
      GLL16(g + go1, lu + 8192);
    }
  };

  bf16x8 a[4][2], bb[4][2];
  auto LDA = [&](int Ab, int qa) {
#pragma unroll
    for (int m2 = 0; m2 < 4; ++m2)
#pragma unroll
      for (int kk = 0; kk < 2; ++kk) {
        int F = ((qa * 4 + m2) * 16 + fr) * 128 + kk * 64 + q16;
        F = SWZ(F);
        a[m2][kk] = *(const bf16x8*)(smem + Ab + F);
      }
  };
  auto LDB = [&](int Bb, int qb) {
#pragma unroll
    for (int n2 = 0; n2 < 2; ++n2)
#pragma unroll
      for (int kk = 0; kk < 2; ++kk) {
        int F = (brow0 + (qb * 2 + n2) * 16 + fr) * 128 + kk * 64 + q16;
        F = SWZ(F);
        bb[qb * 2 + n2][kk] = *(const bf16x8*)(smem + Bb + F);
      }
  };

  f32x4 acc[8][4] = {};

  // prologue: stage tile 0 (buf0) only; tile 1 staged in it=0 ph1
  STAGE4(0);
  VMCNT_LIT(0);
  BAR();

#pragma unroll 1
  for (int it = 0; it < 8; ++it) {
    const bool sB = (2 * it + 2 < 16);
    // ph1: burst-stage tile 2it+1 -> buf1; consume buf0 quad(0,0)
    LDA(Abase0, 0); LDB(Bbase0, 0);
    STAGE4(2 * it + 1);
    BAR(); LGKM0; PRIO1; QUAD(0, 0); PRIO0; BAR();
    // ph2
    LDB(Bbase0, 1);
    BAR(); LGKM0; PRIO1; QUAD(0, 1); PRIO0; BAR();
    // ph3
    LDA(Abase0, 1);
    BAR(); LGKM0; PRIO1; QUAD(1, 1); PRIO0; BAR();
    // ph4: wait tile 2it+1 landed (only its 8 loads in flight)
    BAR(); PRIO1; QUAD(1, 0); PRIO0; VMCNT_LIT(0); BAR();
    // ph5: burst-stage tile 2it+2 -> buf0; consume buf1 quad(0,0)
    LDA(Abase1, 0); LDB(Bbase1, 0);
    if (sB) STAGE4(2 * it + 2);
    BAR(); LGKM0; PRIO1; QUAD(0, 0); PRIO0; BAR();
    // ph6
    LDB(Bbase1, 1);
    BAR(); LGKM0; PRIO1; QUAD(0, 1); PRIO0; BAR();
    // ph7
    LDA(Abase1, 1);
    BAR(); LGKM0; PRIO1; QUAD(1, 1); PRIO0; BAR();
    // ph8: wait tile 2it+2 landed
    BAR(); PRIO1; QUAD(1, 0); PRIO0; VMCNT_LIT(0); BAR();
  }

  // ---- epilogue: exchange s3 via LDS, w1-side waves write h ----
  __syncthreads();
  float* sm = (float*)smem;
  const int col = lane & 15, r4 = (lane >> 4) * 4;
  const int ebase = (wm * 2 + (wn & 1)) * 8192;
  if (wn >= 2) {
#pragma unroll
    for (int mf = 0; mf < 8; ++mf)
#pragma unroll
      for (int nf = 0; nf < 4; ++nf)
#pragma unroll
        for (int i = 0; i < 4; ++i)
          sm[ebase + (mf * 16 + r4 + i) * 64 + nf * 16 + col] = acc[mf][nf][i];
  }
  __syncthreads();
  if (wn < 2) {
#pragma unroll
    for (int mf = 0; mf < 8; ++mf)
#pragma unroll
      for (int nf = 0; nf < 4; ++nf)
#pragma unroll
        for (int i = 0; i < 4; ++i) {
          float s1 = acc[mf][nf][i];
          float s3 = sm[ebase + (mf * 16 + r4 + i) * 64 + nf * 16 + col];
          float hv = (s1 / (1.f + __expf(-s1))) * s3;
          int c = c0 + wm * 128 + mf * 16 + r4 + i;
          int f = f0 + wn * 64 + nf * 16 + col;
          h[(size_t)(e * CAP + c) * F_DIM + f] = f2bf(hv);
        }
  }
}

// ---------------- GEMM2: 256x256 8-phase, BK=64, 8 waves ----------------
// A = h rows [c0,c0+256) over K=F; B rows = w2[e][d0..d0+256), K=F.
// Waves 2m x 4n, each owns 128x64 fp32 out; direct store (no exchange).
__global__ __launch_bounds__(512) void gemm2_kernel(
    const unsigned short* __restrict__ h,    // [ROWS][F]
    const unsigned short* __restrict__ w2b,  // [E][D][F]
    float* __restrict__ eo) {                // [ROWS][D]
  __shared__ __align__(16) char smem[131072];
  const int e = blockIdx.z, c0 = blockIdx.y * 256, d0 = blockIdx.x * 256;
  const int tid = threadIdx.x, w = tid >> 6, lane = tid & 63;
  const int wm = w >> 2, wn = w & 3;
  const int fr = lane & 15, q16 = (lane >> 4) * 16;
  const int brow0 = (wn & 1) * 64;
  const int Abase0 = (0 + wm) * 16384;
  const int Abase1 = (2 + wm) * 16384;
  const int Bbase0 = 65536 + (0 + (wn >> 1)) * 16384;
  const int Bbase1 = 65536 + (2 + (wn >> 1)) * 16384;

  const int L0 = w * 1024 + lane * 16;
  const int L1 = 8192 + L0;
  const int P0 = SWZ(L0);
  const int P1 = SWZ(L1);
  // row stride here is F*2 = 8192 B
  const size_t go0 = (size_t)(P0 >> 7) * 8192 + (P0 & 127);
  const size_t go1 = (size_t)(P1 >> 7) * 8192 + (P1 & 127);
  const char* gb0 = (const char*)(w2b + ((size_t)e * D_DIM + d0) * F_DIM);
  const char* gb1 = (const char*)(w2b + ((size_t)e * D_DIM + d0 + 128) * F_DIM);
  const char* gb2 = (const char*)(h + (size_t)(e * CAP + c0) * F_DIM);
  const char* gb3 = (const char*)(h + (size_t)(e * CAP + c0 + 128) * F_DIM);

  auto STAGE4 = [&](int t) {
    int b = (t & 1) * 2;
#pragma unroll
    for (int ht = 0; ht < 4; ++ht) {
      int lb = ((ht >= 2) ? 0 : 65536) + (b + (ht & 1)) * 16384;
      const char* g = (ht == 0 ? gb0 : ht == 1 ? gb1 : ht == 2 ? gb2 : gb3)
                      + (size_t)t * 128;
      char* lu = smem + lb + w * 1024;
      GLL16(g + go0, lu);
      GLL16(g + go1, lu + 8192);
    }
  };

  bf16x8 a[4][2], bb[4][2];
  auto LDA = [&](int Ab, int qa) {
#pragma unroll
    for (int m2 = 0; m2 < 4; ++m2)
#pragma unroll
      for (int kk = 0; kk < 2; ++kk) {
        int F = ((qa * 4 + m2) * 16 + fr) * 128 + kk * 64 + q16;
        F = SWZ(F);
        a[m2][kk] = *(const bf16x8*)(smem + Ab + F);
      }
  };
  auto LDB = [&](int Bb, int qb) {
#pragma unroll
    for (int n2 = 0; n2 < 2; ++n2)
#pragma unroll
      for (int kk = 0; kk < 2; ++kk) {
        int F = (brow0 + (qb * 2 + n2) * 16 + fr) * 128 + kk * 64 + q16;
        F = SWZ(F);
        bb[qb * 2 + n2][kk] = *(const bf16x8*)(smem + Bb + F);
      }
  };

  f32x4 acc[8][4] = {};

  STAGE4(0);
  VMCNT_LIT(0);
  BAR();

#pragma unroll 1
  for (int it = 0; it < 32; ++it) {
    const bool sB = (2 * it + 2 < 64);
    LDA(Abase0, 0); LDB(Bbase0, 0);
    STAGE4(2 * it + 1);
    BAR(); LGKM0; PRIO1; QUAD(0, 0); PRIO0; BAR();
    LDB(Bbase0, 1);
    BAR(); LGKM0; PRIO1; QUAD(0, 1); PRIO0; BAR();
    LDA(Abase0, 1);
    BAR(); LGKM0; PRIO1; QUAD(1, 1); PRIO0; BAR();
    BAR(); PRIO1; QUAD(1, 0); PRIO0; VMCNT_LIT(0); BAR();
    LDA(Abase1, 0); LDB(Bbase1, 0);
    if (sB) STAGE4(2 * it + 2);
    BAR(); LGKM0; PRIO1; QUAD(0, 0); PRIO0; BAR();
    LDB(Bbase1, 1);
    BAR(); LGKM0; PRIO1; QUAD(0, 1); PRIO0; BAR();
    LDA(Abase1, 1);
    BAR(); LGKM0; PRIO1; QUAD(1, 1); PRIO0; BAR();
    BAR(); PRIO1; QUAD(1, 0); PRIO0; VMCNT_LIT(0); BAR();
  }

  // epilogue: direct f32 store of each wave's 128x64 block
  const int col = lane & 15, r4 = (lane >> 4) * 4;
#pragma unroll
  for (int mf = 0; mf < 8; ++mf)
#pragma unroll
    for (int nf = 0; nf < 4; ++nf)
#pragma unroll
      for (int i = 0; i < 4; ++i) {
        int c = c0 + wm * 128 + mf * 16 + r4 + i;
        int d = d0 + wn * 64 + nf * 16 + col;
        eo[(size_t)(e * CAP + c) * D_DIM + d] = acc[mf][nf][i];
      }
}

// ---------------- combine: y[t] = w0*eo[r0] + w1*eo[r1] ----------------
__global__ void combine_kernel(const float* __restrict__ eo,
                               const int* __restrict__ slot,
                               const float2* __restrict__ rw,
                               float* __restrict__ y) {
  int t = blockIdx.x, lane = threadIdx.x;   // 64 threads
  int r0 = slot[2 * t], r1 = slot[2 * t + 1];
  float2 w = rw[t];
  float w0 = (r0 < ROWS) ? w.x : 0.f;
  float w1v = (r1 < ROWS) ? w.y : 0.f;
  if (r0 >= ROWS) r0 = 0;
  if (r1 >= ROWS) r1 = 0;
  const float4* a = (const float4*)(eo + (size_t)r0 * D_DIM);
  const float4* b = (const float4*)(eo + (size_t)r1 * D_DIM);
  float4* yo = (float4*)(y + (size_t)t * D_DIM);
#pragma unroll
  for (int j = 0; j < 4; ++j) {
    float4 va = a[j * 64 + lane], vb = b[j * 64 + lane];
    float4 o;
    o.x = w0 * va.x + w1v * vb.x;
    o.y = w0 * va.y + w1v * vb.y;
    o.z = w0 * va.z + w1v * vb.z;
    o.w = w0 * va.w + w1v * vb.w;
    yo[j * 64 + lane] = o;
  }
}

// ---------------- launch ----------------
extern "C" void kernel_launch(void* const* d_in, const int* in_sizes, int n_in,
                              void* d_out, int out_size, void* d_ws, size_t ws_size,
                              hipStream_t stream) {
  const float* x  = (const float*)d_in[0];
  const float* gw = (const float*)d_in[1];
  const float* w1 = (const float*)d_in[2];
  const float* w3 = (const float*)d_in[3];
  const float* w2 = (const float*)d_in[4];
  float* y   = (float*)d_out;
  float* aux = y + (size_t)T_TOK * D_DIM;

  char* ws = (char*)d_ws;
  unsigned short* w1b = (unsigned short*)(ws);
  unsigned short* w3b = (unsigned short*)(ws + 67108864);
  unsigned short* w2b = w1b;                          // after gemm1
  float*          eo  = (float*)(ws + 67108864);      // after gemm1 (over w3b)
  unsigned short* eb  = (unsigned short*)(ws + 134217728);
  unsigned short* hbuf= (unsigned short*)(ws + 155189248);
  int2*   idx    = (int2*)(ws + 239075328);
  float2* rw     = (float2*)(ws + 239140864);
  int*    slot   = (int*)(ws + 239206400);
  int*    counts = (int*)(ws + 239271936);
  float*  probs  = (float*)(ws + 239271968);

  hipMemsetAsync(counts, 0, 64, stream);
  convert_kernel<<<2048, 256, 0, stream>>>((const float4*)w1, (ushort4*)w1b, 8388608);
  convert_kernel<<<2048, 256, 0, stream>>>((const float4*)w3, (ushort4*)w3b, 8388608);
  router_kernel<<<T_TOK / 4, 256, 0, stream>>>(x, gw, idx, rw, counts, probs);
  scan_kernel<<<1, 1024, 0, stream>>>(idx, slot, counts, probs, aux);
  dispatch_kernel<<<T_TOK * 2, 64, 0, stream>>>(x, slot, eb);
  gemm1_kernel<<<dim3(F_DIM / 128, CAP / 256, E_NUM), 512, 0, stream>>>(eb, w1b, w3b, hbuf);
  convert_kernel<<<2048, 256, 0, stream>>>((const float4*)w2, (ushort4*)w2b, 8388608);
  gemm2_kernel<<<dim3(D_DIM / 256, CAP / 256, E_NUM), 512, 0, stream>>>(hbuf, w2b, eo);
  combine_kernel<<<T_TOK, 64, 0, stream>>>(eo, slot, rw, y);
}

// Round 7
// 799.882 us; speedup vs baseline: 1.0317x; 1.0317x over previous
//
#include <hip/hip_runtime.h>
#include <hip/hip_bf16.h>
#include <cstdint>

// ---- problem constants (B=4,S=2048,D=1024,E=8,F=4096, top-2, cap 1.25) ----
#define T_TOK 8192
#define D_DIM 1024
#define E_NUM 8
#define F_DIM 4096
#define CAP   1280          // ceil(8192*1.25/8)
#define ROWS  (E_NUM*CAP)   // 10240 (row index ROWS == dump/dropped)

typedef float  f32x4  __attribute__((ext_vector_type(4)));
typedef __bf16 bf16x8 __attribute__((ext_vector_type(8)));

__device__ __forceinline__ unsigned short f2bf(float f) {
  union { float f; unsigned int u; } v; v.f = f;
  unsigned int r = v.u + 0x7FFFu + ((v.u >> 16) & 1u);   // RNE
  return (unsigned short)(r >> 16);
}

// async global->LDS, 16B per lane; LDS dest is wave-uniform base + lane*16
#define GLL16(g, l) __builtin_amdgcn_global_load_lds( \
    (__attribute__((address_space(1))) void*)(g),      \
    (__attribute__((address_space(3))) void*)(l), 16, 0, 0)

#define BAR() __builtin_amdgcn_s_barrier()
#define PRIO1 __builtin_amdgcn_s_setprio(1)
#define PRIO0 __builtin_amdgcn_s_setprio(0)
#define LGKM0 do { asm volatile("s_waitcnt lgkmcnt(0)" ::: "memory"); \
                   __builtin_amdgcn_sched_barrier(0); } while (0)
#define VMCNT_LIT(n) asm volatile("s_waitcnt vmcnt(" #n ")" ::: "memory")
// bank-conflict swizzle for [rows][128B] LDS tiles: XOR 16B-chunk idx (bits
// 4-6) with row&7 (bits 7-9). Involution; same map on write-source and read.
#define SWZ(X) ((X) ^ ((((X) >> 7) & 7) << 4))

// ---------------- fp32 -> bf16 weight conversion ----------------
__global__ void convert_kernel(const float4* __restrict__ src,
                               ushort4* __restrict__ dst, int n4) {
  int i = blockIdx.x * blockDim.x + threadIdx.x;
  int stride = gridDim.x * blockDim.x;
  for (; i < n4; i += stride) {
    float4 v = src[i];
    ushort4 o;
    o.x = f2bf(v.x); o.y = f2bf(v.y); o.z = f2bf(v.z); o.w = f2bf(v.w);
    dst[i] = o;
  }
}

// ---------------- router: fp32 logits, top-2, softmax, aux accum ----------------
__global__ __launch_bounds__(256) void router_kernel(
    const float* __restrict__ x, const float* __restrict__ gw,
    int2* __restrict__ idx, float2* __restrict__ rw,
    int* __restrict__ counts, float* __restrict__ probs_sum) {
  __shared__ float gws[E_NUM * D_DIM];      // 32 KB
  __shared__ float lprob[E_NUM];
  __shared__ int   lcnt[E_NUM];
  int tid = threadIdx.x;
  {
    const float4* s = (const float4*)gw;
    float4* d = (float4*)gws;
    for (int i = tid; i < (E_NUM * D_DIM) / 4; i += 256) d[i] = s[i];
  }
  if (tid < E_NUM) { lprob[tid] = 0.f; lcnt[tid] = 0; }
  __syncthreads();

  int wave = tid >> 6, lane = tid & 63;
  int t = blockIdx.x * 4 + wave;
  float acc[E_NUM] = {};
  for (int i = 0; i < D_DIM / 64; ++i) {
    int d = i * 64 + lane;
    float xv = x[(size_t)t * D_DIM + d];
#pragma unroll
    for (int e = 0; e < E_NUM; ++e) acc[e] += xv * gws[e * D_DIM + d];
  }
#pragma unroll
  for (int e = 0; e < E_NUM; ++e)
#pragma unroll
    for (int off = 32; off; off >>= 1) acc[e] += __shfl_xor(acc[e], off);

  if (lane == 0) {
    int i1 = 0; float v1 = acc[0];
#pragma unroll
    for (int e = 1; e < E_NUM; ++e) if (acc[e] > v1) { v1 = acc[e]; i1 = e; }
    int i2 = -1; float v2 = -3.4e38f;
#pragma unroll
    for (int e = 0; e < E_NUM; ++e)
      if (e != i1 && acc[e] > v2) { v2 = acc[e]; i2 = e; }
    float e2 = expf(v2 - v1);          // v1 >= v2
    float s  = 1.f + e2;
    int2 ii; ii.x = i1; ii.y = i2; idx[t] = ii;
    float2 ww; ww.x = 1.f / s; ww.y = e2 / s; rw[t] = ww;
    atomicAdd(&lcnt[i1], 1); atomicAdd(&lcnt[i2], 1);
    float se = 0.f, p[E_NUM];
#pragma unroll
    for (int e = 0; e < E_NUM; ++e) { p[e] = expf(acc[e] - v1); se += p[e]; }
    float inv = 1.f / se;
#pragma unroll
    for (int e = 0; e < E_NUM; ++e) atomicAdd(&lprob[e], p[e] * inv);
  }
  __syncthreads();
  if (tid < E_NUM) {
    atomicAdd(&probs_sum[tid], lprob[tid]);
    atomicAdd(&counts[tid], lcnt[tid]);
  }
}

// ---------------- capacity scan (order-exact cumsum over 16384 slots) + aux ----------------
__global__ __launch_bounds__(1024) void scan_kernel(
    const int2* __restrict__ idx, int* __restrict__ slot,
    const int* __restrict__ counts, const float* __restrict__ probs_sum,
    float* __restrict__ aux) {
  __shared__ int sc[1024][E_NUM];   // 32 KB
  int tid = threadIdx.x;
  int fe[16];
  int lc[E_NUM] = {};
#pragma unroll
  for (int j = 0; j < 16; ++j) {
    int s = tid * 16 + j;
    int2 p = idx[s >> 1];
    int e = (s & 1) ? p.y : p.x;
    fe[j] = e; lc[e]++;
  }
#pragma unroll
  for (int e = 0; e < E_NUM; ++e) sc[tid][e] = lc[e];
  __syncthreads();
  for (int off = 1; off < 1024; off <<= 1) {
    int v[E_NUM];
    bool has = (tid >= off);
    if (has) {
#pragma unroll
      for (int e = 0; e < E_NUM; ++e) v[e] = sc[tid - off][e];
    }
    __syncthreads();
    if (has) {
#pragma unroll
      for (int e = 0; e < E_NUM; ++e) sc[tid][e] += v[e];
    }
    __syncthreads();
  }
  int pre[E_NUM];
#pragma unroll
  for (int e = 0; e < E_NUM; ++e) pre[e] = tid ? sc[tid - 1][e] : 0;
  int run[E_NUM] = {};
#pragma unroll
  for (int j = 0; j < 16; ++j) {
    int e = fe[j];
    int rank = pre[e] + run[e];
    run[e]++;
    slot[tid * 16 + j] = (rank < CAP) ? (e * CAP + rank) : ROWS;
  }
  if (tid == 0) {
    float s = 0.f;
    for (int e = 0; e < E_NUM; ++e) s += (float)counts[e] * probs_sum[e];
    aux[0] = 0.01f * (float)E_NUM * s / ((float)T_TOK * (float)T_TOK);
  }
}

// ---------------- dispatch x -> eb (bf16), skip dropped slots ----------------
__global__ void dispatch_kernel(const float* __restrict__ x,
                                const int* __restrict__ slot,
                                unsigned short* __restrict__ eb) {
  int s = blockIdx.x, lane = threadIdx.x;   // 64 threads
  int row = slot[s];
  if (row >= ROWS) return;
  int t = s >> 1;
  const float4* xs = (const float4*)(x + (size_t)t * D_DIM);
  ushort4* ed = (ushort4*)(eb + (size_t)row * D_DIM);
#pragma unroll
  for (int j = 0; j < 4; ++j) {
    float4 v = xs[j * 64 + lane];
    ushort4 o;
    o.x = f2bf(v.x); o.y = f2bf(v.y); o.z = f2bf(v.z); o.w = f2bf(v.w);
    ed[j * 64 + lane] = o;
  }
}

// ---- shared 8-phase K-loop machinery (BK=64, 8 waves, dbuf) ----
#define QUAD(QA, QB) \
  { _Pragma("unroll") for (int m2 = 0; m2 < 4; ++m2) { \
    _Pragma("unroll") for (int n2 = 0; n2 < 2; ++n2) { \
      acc[(QA)*4+m2][(QB)*2+n2] = __builtin_amdgcn_mfma_f32_16x16x32_bf16( \
        a[m2][0], bb[(QB)*2+n2][0], acc[(QA)*4+m2][(QB)*2+n2], 0, 0, 0); \
      acc[(QA)*4+m2][(QB)*2+n2] = __builtin_amdgcn_mfma_f32_16x16x32_bf16( \
        a[m2][1], bb[(QB)*2+n2][1], acc[(QA)*4+m2][(QB)*2+n2], 0, 0, 0); \
  } } }

// ---------------- GEMM1: 256x(128+128) 8-phase, BK=64, 8 waves ----------------
// R3-proven schedule (spread staging, counted vmcnt(2)) + T1 XCD swizzle.
// A = eb rows [c0,c0+256); B rows 0-127 = w1[f0..f0+128), 128-255 = w3[...).
// Waves: wm=w>>2 (A-half), wn=w&3; wn<2 -> s1, wn>=2 -> s3 (same cols).
// Epilogue: w3 waves dump acc (f32) to LDS; w1 waves compute silu(s1)*s3.
__global__ __launch_bounds__(512) void gemm1_kernel(
    const unsigned short* __restrict__ eb,   // [ROWS][D]
    const unsigned short* __restrict__ w1b,  // [E][F][D]
    const unsigned short* __restrict__ w3b,
    unsigned short* __restrict__ h) {        // [ROWS][F]
  __shared__ __align__(16) char smem[131072];
  // T1: bijective XCD swizzle (nwg=1280, 1280%8==0): each XCD gets a
  // contiguous chunk of the logical grid -> A-panel reuse within XCD L2.
  int lin = blockIdx.x + 32 * (blockIdx.y + 5 * blockIdx.z);
  lin = (lin & 7) * 160 + (lin >> 3);
  const int e = lin / 160, c0 = ((lin / 32) % 5) * 256, f0 = (lin & 31) * 128;
  const int tid = threadIdx.x, w = tid >> 6, lane = tid & 63;
  const int wm = w >> 2, wn = w & 3;
  const int fr = lane & 15, q16 = (lane >> 4) * 16;
  const int brow0 = (wn & 1) * 64;
  const int Abase0 = (0 + wm) * 16384;
  const int Abase1 = (2 + wm) * 16384;
  const int Bbase0 = 65536 + (0 + (wn >> 1)) * 16384;
  const int Bbase1 = 65536 + (2 + (wn >> 1)) * 16384;

  // staging: per-lane linear LDS offsets and inverse-swizzled global offsets
  const int L0 = w * 1024 + lane * 16;
  const int L1 = 8192 + L0;
  const int P0 = SWZ(L0);
  const int P1 = SWZ(L1);
  const size_t go0 = (size_t)(P0 >> 7) * 2048 + (P0 & 127);
  const size_t go1 = (size_t)(P1 >> 7) * 2048 + (P1 & 127);
  const char* gb0 = (const char*)(w1b + ((size_t)e * F_DIM + f0) * D_DIM);
  const char* gb1 = (const char*)(w3b + ((size_t)e * F_DIM + f0) * D_DIM);
  const char* gb2 = (const char*)(eb + (size_t)(e * CAP + c0) * D_DIM);
  const char* gb3 = (const char*)(eb + (size_t)(e * CAP + c0 + 128) * D_DIM);

  auto STAGE = [&](int t, int ht) {
    int lb = ((ht >= 2) ? 0 : 65536) + ((t & 1) * 2 + (ht & 1)) * 16384;
    const char* g = (ht == 0 ? gb0 : ht == 1 ? gb1 : ht == 2 ? gb2 : gb3)
                    + (size_t)t * 128;
    char* lu = smem + lb + w * 1024;
    GLL16(g + go0, lu);
    GLL16(g + go1, lu + 8192);
  };

  bf16x8 a[4][2], bb[4][2];
  auto LDA = [&](int Ab, int qa) {
#pragma unroll
    for (int m2 = 0; m2 < 4; ++m2)
#pragma unroll
      for (int kk = 0; kk < 2; ++kk) {
        int F = ((qa * 4 + m2) * 16 + fr) * 128 + kk * 64 + q16;
        F = SWZ(F);
        a[m2][kk] = *(const bf16x8*)(smem + Ab + F);
      }
  };
  auto LDB = [&](int Bb, int qb) {
#pragma unroll
    for (int n2 = 0; n2 < 2; ++n2)
#pragma unroll
      for (int kk = 0; kk < 2; ++kk) {
        int F = (brow0 + (qb * 2 + n2) * 16 + fr) * 128 + kk * 64 + q16;
        F = SWZ(F);
        bb[qb * 2 + n2][kk] = *(const bf16x8*)(smem + Bb + F);
      }
  };

  f32x4 acc[8][4] = {};

  // prologue: stage tiles 0 and 1 fully (16 loads), wait tile0
#pragma unroll
  for (int t = 0; t < 2; ++t)
#pragma unroll
    for (int ht = 0; ht < 4; ++ht) STAGE(t, ht);
  VMCNT_LIT(8);
  BAR();

#pragma unroll 1
  for (int it = 0; it < 8; ++it) {
    const int t1 = 2 * it + 1, t2 = 2 * it + 2, t3 = 2 * it + 3;
    const bool sA = (it > 0);
    const bool sB = (t2 < 16);
    const bool sC = (t3 < 16);
    // ph1: tile 2it (buf0), quad(0,0)
    LDA(Abase0, 0); LDB(Bbase0, 0);
    if (sA) STAGE(t1, 1);
    BAR(); LGKM0; PRIO1; QUAD(0, 0); PRIO0; BAR();
    // ph2: quad(0,1)
    LDB(Bbase0, 1);
    if (sA) STAGE(t1, 2);
    BAR(); LGKM0; PRIO1; QUAD(0, 1); PRIO0; BAR();
    // ph3: quad(1,1)
    LDA(Abase0, 1);
    if (sA) STAGE(t1, 3);
    BAR(); LGKM0; PRIO1; QUAD(1, 1); PRIO0; BAR();
    // ph4: quad(1,0); counted vmcnt gates tile t1 (consumed ph5)
    if (sB) { STAGE(t2, 0); VMCNT_LIT(2); } else { VMCNT_LIT(0); }
    BAR(); PRIO1; QUAD(1, 0); PRIO0; BAR();
    // ph5: tile 2it+1 (buf1), quad(0,0)
    LDA(Abase1, 0); LDB(Bbase1, 0);
    if (sB) STAGE(t2, 1);
    BAR(); LGKM0; PRIO1; QUAD(0, 0); PRIO0; BAR();
    // ph6: quad(0,1)
    LDB(Bbase1, 1);
    if (sB) STAGE(t2, 2);
    BAR(); LGKM0; PRIO1; QUAD(0, 1); PRIO0; BAR();
    // ph7: quad(1,1)
    LDA(Abase1, 1);
    if (sB) STAGE(t2, 3);
    BAR(); LGKM0; PRIO1; QUAD(1, 1); PRIO0; BAR();
    // ph8: quad(1,0); counted vmcnt gates tile t2 (consumed next ph1)
    if (sC) { STAGE(t3, 0); VMCNT_LIT(2); } else { VMCNT_LIT(0); }
    BAR(); PRIO1; QUAD(1, 0); PRIO0; BAR();
  }

  // ---- epilogue: exchange s3 via LDS, w1-side waves write h ----
  __syncthreads();
  float* sm = (float*)smem;
  const int col = lane & 15, r4 = (lane >> 4) * 4;
  const int ebase = (wm * 2 + (wn & 1)) * 8192;
  if (wn >= 2) {
#pragma unroll
    for (int mf = 0; mf < 8; ++mf)
#pragma unroll
      for (int nf = 0; nf < 4; ++nf)
#pragma unroll
        for (int i = 0; i < 4; ++i)
          sm[ebase + (mf * 16 + r4 + i) * 64 + nf * 16 + col] = acc[mf][nf][i];
  }
  __syncthreads();
  if (wn < 2) {
#pragma unroll
    for (int mf = 0; mf < 8; ++mf)
#pragma unroll
      for (int nf = 0; nf < 4; ++nf)
#pragma unroll
        for (int i = 0; i < 4; ++i) {
          float s1 = acc[mf][nf][i];
          float s3 = sm[ebase + (mf * 16 + r4 + i) * 64 + nf * 16 + col];
          float hv = (s1 / (1.f + __expf(-s1))) * s3;
          int c = c0 + wm * 128 + mf * 16 + r4 + i;
          int f = f0 + wn * 64 + nf * 16 + col;
          h[(size_t)(e * CAP + c) * F_DIM + f] = f2bf(hv);
        }
  }
}

// ---------------- GEMM2: 256x256 8-phase, BK=64, 8 waves ----------------
// A = h rows [c0,c0+256) over K=F; B rows = w2[e][d0..d0+256), K=F.
// Waves 2m x 4n, each owns 128x64 fp32 out; direct store. + T1 XCD swizzle.
__global__ __launch_bounds__(512) void gemm2_kernel(
    const unsigned short* __restrict__ h,    // [ROWS][F]
    const unsigned short* __restrict__ w2b,  // [E][D][F]
    float* __restrict__ eo) {                // [ROWS][D]
  __shared__ __align__(16) char smem[131072];
  // T1: nwg=160, 160%8==0 -> simple bijective chunking
  int lin = blockIdx.x + 4 * (blockIdx.y + 5 * blockIdx.z);
  lin = (lin & 7) * 20 + (lin >> 3);
  const int e = lin / 20, c0 = ((lin / 4) % 5) * 256, d0 = (lin & 3) * 256;
  const int tid = threadIdx.x, w = tid >> 6, lane = tid & 63;
  const int wm = w >> 2, wn = w & 3;
  const int fr = lane & 15, q16 = (lane >> 4) * 16;
  const int brow0 = (wn & 1) * 64;
  const int Abase0 = (0 + wm) * 16384;
  const int Abase1 = (2 + wm) * 16384;
  const int Bbase0 = 65536 + (0 + (wn >> 1)) * 16384;
  const int Bbase1 = 65536 + (2 + (wn >> 1)) * 16384;

  const int L0 = w * 1024 + lane * 16;
  const int L1 = 8192 + L0;
  const int P0 = SWZ(L0);
  const int P1 = SWZ(L1);
  // row stride here is F*2 = 8192 B
  const size_t go0 = (size_t)(P0 >> 7) * 8192 + (P0 & 127);
  const size_t go1 = (size_t)(P1 >> 7) * 8192 + (P1 & 127);
  const char* gb0 = (const char*)(w2b + ((size_t)e * D_DIM + d0) * F_DIM);
  const char* gb1 = (const char*)(w2b + ((size_t)e * D_DIM + d0 + 128) * F_DIM);
  const char* gb2 = (const char*)(h + (size_t)(e * CAP + c0) * F_DIM);
  const char* gb3 = (const char*)(h + (size_t)(e * CAP + c0 + 128) * F_DIM);

  auto STAGE4 = [&](int t) {
    int b = (t & 1) * 2;
#pragma unroll
    for (int ht = 0; ht < 4; ++ht) {
      int lb = ((ht >= 2) ? 0 : 65536) + (b + (ht & 1)) * 16384;
      const char* g = (ht == 0 ? gb0 : ht == 1 ? gb1 : ht == 2 ? gb2 : gb3)
                      + (size_t)t * 128;
      char* lu = smem + lb + w * 1024;
      GLL16(g + go0, lu);
      GLL16(g + go1, lu + 8192);
    }
  };

  bf16x8 a[4][2], bb[4][2];
  auto LDA = [&](int Ab, int qa) {
#pragma unroll
    for (int m2 = 0; m2 < 4; ++m2)
#pragma unroll
      for (int kk = 0; kk < 2; ++kk) {
        int F = ((qa * 4 + m2) * 16 + fr) * 128 + kk * 64 + q16;
        F = SWZ(F);
        a[m2][kk] = *(const bf16x8*)(smem + Ab + F);
      }
  };
  auto LDB = [&](int Bb, int qb) {
#pragma unroll
    for (int n2 = 0; n2 < 2; ++n2)
#pragma unroll
      for (int kk = 0; kk < 2; ++kk) {
        int F = (brow0 + (qb * 2 + n2) * 16 + fr) * 128 + kk * 64 + q16;
        F = SWZ(F);
        bb[qb * 2 + n2][kk] = *(const bf16x8*)(smem + Bb + F);
      }
  };

  f32x4 acc[8][4] = {};

  STAGE4(0);
  VMCNT_LIT(0);
  BAR();

#pragma unroll 1
  for (int it = 0; it < 32; ++it) {
    const bool sB = (2 * it + 2 < 64);
    LDA(Abase0, 0); LDB(Bbase0, 0);
    STAGE4(2 * it + 1);
    BAR(); LGKM0; PRIO1; QUAD(0, 0); PRIO0; BAR();
    LDB(Bbase0, 1);
    BAR(); LGKM0; PRIO1; QUAD(0, 1); PRIO0; BAR();
    LDA(Abase0, 1);
    BAR(); LGKM0; PRIO1; QUAD(1, 1); PRIO0; BAR();
    BAR(); PRIO1; QUAD(1, 0); PRIO0; VMCNT_LIT(0); BAR();
    LDA(Abase1, 0); LDB(Bbase1, 0);
    if (sB) STAGE4(2 * it + 2);
    BAR(); LGKM0; PRIO1; QUAD(0, 0); PRIO0; BAR();
    LDB(Bbase1, 1);
    BAR(); LGKM0; PRIO1; QUAD(0, 1); PRIO0; BAR();
    LDA(Abase1, 1);
    BAR(); LGKM0; PRIO1; QUAD(1, 1); PRIO0; BAR();
    BAR(); PRIO1; QUAD(1, 0); PRIO0; VMCNT_LIT(0); BAR();
  }

  // epilogue: direct f32 store of each wave's 128x64 block
  const int col = lane & 15, r4 = (lane >> 4) * 4;
#pragma unroll
  for (int mf = 0; mf < 8; ++mf)
#pragma unroll
    for (int nf = 0; nf < 4; ++nf)
#pragma unroll
      for (int i = 0; i < 4; ++i) {
        int c = c0 + wm * 128 + mf * 16 + r4 + i;
        int d = d0 + wn * 64 + nf * 16 + col;
        eo[(size_t)(e * CAP + c) * D_DIM + d] = acc[mf][nf][i];
      }
}

// ---------------- combine: y[t] = w0*eo[r0] + w1*eo[r1] ----------------
__global__ void combine_kernel(const float* __restrict__ eo,
                               const int* __restrict__ slot,
                               const float2* __restrict__ rw,
                               float* __restrict__ y) {
  int t = blockIdx.x, lane = threadIdx.x;   // 64 threads
  int r0 = slot[2 * t], r1 = slot[2 * t + 1];
  float2 w = rw[t];
  float w0 = (r0 < ROWS) ? w.x : 0.f;
  float w1v = (r1 < ROWS) ? w.y : 0.f;
  if (r0 >= ROWS) r0 = 0;
  if (r1 >= ROWS) r1 = 0;
  const float4* a = (const float4*)(eo + (size_t)r0 * D_DIM);
  const float4* b = (const float4*)(eo + (size_t)r1 * D_DIM);
  float4* yo = (float4*)(y + (size_t)t * D_DIM);
#pragma unroll
  for (int j = 0; j < 4; ++j) {
    float4 va = a[j * 64 + lane], vb = b[j * 64 + lane];
    float4 o;
    o.x = w0 * va.x + w1v * vb.x;
    o.y = w0 * va.y + w1v * vb.y;
    o.z = w0 * va.z + w1v * vb.z;
    o.w = w0 * va.w + w1v * vb.w;
    yo[j * 64 + lane] = o;
  }
}

// ---------------- launch ----------------
extern "C" void kernel_launch(void* const* d_in, const int* in_sizes, int n_in,
                              void* d_out, int out_size, void* d_ws, size_t ws_size,
                              hipStream_t stream) {
  const float* x  = (const float*)d_in[0];
  const float* gw = (const float*)d_in[1];
  const float* w1 = (const float*)d_in[2];
  const float* w3 = (const float*)d_in[3];
  const float* w2 = (const float*)d_in[4];
  float* y   = (float*)d_out;
  float* aux = y + (size_t)T_TOK * D_DIM;

  char* ws = (char*)d_ws;
  unsigned short* w1b = (unsigned short*)(ws);
  unsigned short* w3b = (unsigned short*)(ws + 67108864);
  unsigned short* w2b = w1b;                          // after gemm1
  float*          eo  = (float*)(ws + 67108864);      // after gemm1 (over w3b)
  unsigned short* eb  = (unsigned short*)(ws + 134217728);
  unsigned short* hbuf= (unsigned short*)(ws + 155189248);
  int2*   idx    = (int2*)(ws + 239075328);
  float2* rw     = (float2*)(ws + 239140864);
  int*    slot   = (int*)(ws + 239206400);
  int*    counts = (int*)(ws + 239271936);
  float*  probs  = (float*)(ws + 239271968);

  hipMemsetAsync(counts, 0, 64, stream);
  convert_kernel<<<2048, 256, 0, stream>>>((const float4*)w1, (ushort4*)w1b, 8388608);
  convert_kernel<<<2048, 256, 0, stream>>>((const float4*)w3, (ushort4*)w3b, 8388608);
  router_kernel<<<T_TOK / 4, 256, 0, stream>>>(x, gw, idx, rw, counts, probs);
  scan_kernel<<<1, 1024, 0, stream>>>(idx, slot, counts, probs, aux);
  dispatch_kernel<<<T_TOK * 2, 64, 0, stream>>>(x, slot, eb);
  gemm1_kernel<<<dim3(F_DIM / 128, CAP / 256, E_NUM), 512, 0, stream>>>(eb, w1b, w3b, hbuf);
  convert_kernel<<<2048, 256, 0, stream>>>((const float4*)w2, (ushort4*)w2b, 8388608);
  gemm2_kernel<<<dim3(D_DIM / 256, CAP / 256, E_NUM), 512, 0, stream>>>(hbuf, w2b, eo);
  combine_kernel<<<T_TOK, 64, 0, stream>>>(eo, slot, rw, y);
}